// Round 1
// baseline (496.786 us; speedup 1.0000x reference)
//
#include <hip/hip_runtime.h>

// ComplexAttention: B=4, S=2048, D=1024. Reduces to single-head attention with
// head_dim 2*D=2048:  Q/K/V = X@W^T+b ; S = Q@K^T/32 ; P = softmax(S) ; O = P@V ;
// out = O@Wo^T + bo.   All GEMMs bf16-MFMA (fp32 accum), m97 structure.

typedef short  bf16x8 __attribute__((ext_vector_type(8)));
typedef float  f32x4  __attribute__((ext_vector_type(4)));

typedef __attribute__((address_space(3))) void       lds_void;
typedef const __attribute__((address_space(1))) void g_void;

__device__ __forceinline__ unsigned short f2bf(float f) {
  union { float f; unsigned u; } v; v.f = f;
  unsigned r = v.u + 0x7FFFu + ((v.u >> 16) & 1u);   // round-to-nearest-even
  return (unsigned short)(r >> 16);
}

// ---------------- fp32 -> bf16 convert (vectorized) ----------------
__global__ __launch_bounds__(256) void cvt_f32_bf16(const float* __restrict__ in,
                                                    unsigned short* __restrict__ out,
                                                    int n4) {
  int i = blockIdx.x * 256 + threadIdx.x;
  if (i >= n4) return;
  const float4 v = ((const float4*)in)[i];
  union { unsigned short us[4]; unsigned long long ll; } u;
  u.us[0] = f2bf(v.x); u.us[1] = f2bf(v.y); u.us[2] = f2bf(v.z); u.us[3] = f2bf(v.w);
  ((unsigned long long*)out)[i] = u.ll;
}

// ---------------- NT GEMM: C[m,n] = alpha * sum_k A[m,k]*B[n,k] (+ bias[n]) ----
// A,B bf16 row-major (K contiguous).  CMODE: 0 = fp32 C, 1 = bf16 C,
// 2 = bf16 transposed-V write: Vt[b][n][t] with b=m>>11, t=m&2047 (hardcoded S=2048).
// m97 structure: 128x128 tile, BK=32, 256 threads = 4 waves (2x2 of 64x64),
// global_load_lds width-16 staging, mfma_f32_16x16x32_bf16, acc[4][4].
template<int CMODE, bool BIAS>
__global__ __launch_bounds__(256) void gemm_nt(const unsigned short* __restrict__ A,
                                               const unsigned short* __restrict__ B,
                                               void* __restrict__ Cv,
                                               const float* __restrict__ bias,
                                               int K, int lda, int ldb, int ldc,
                                               long bsA, long bsB, long bsC,
                                               float alpha)
{
  __shared__ unsigned short As[128 * 32];
  __shared__ unsigned short Bs[128 * 32];
  const int bz = blockIdx.z;
  const unsigned short* Ab = A + (long)bz * bsA;
  const unsigned short* Bb = B + (long)bz * bsB;
  const int m0 = blockIdx.y * 128, n0 = blockIdx.x * 128;
  const int tid = threadIdx.x;
  const int lane = tid & 63, wid = tid >> 6;
  const int wm = (wid >> 1) * 64, wn = (wid & 1) * 64;
  f32x4 acc[4][4] = {};

  const int o0 = wid * 2048 + lane * 16;       // byte offset of lane's 16B chunk in tile
  for (int k0 = 0; k0 < K; k0 += 32) {
#pragma unroll
    for (int j = 0; j < 2; ++j) {
      const int o  = o0 + j * 1024;            // tile is 128 rows x 64B
      const int r  = o >> 6;                   // row
      const int ce = (o & 63) >> 1;            // elem within row
      __builtin_amdgcn_global_load_lds(
          (g_void*)(Ab + (long)(m0 + r) * lda + k0 + ce),
          (lds_void*)((char*)As + wid * 2048 + j * 1024), 16, 0, 0);
      __builtin_amdgcn_global_load_lds(
          (g_void*)(Bb + (long)(n0 + r) * ldb + k0 + ce),
          (lds_void*)((char*)Bs + wid * 2048 + j * 1024), 16, 0, 0);
    }
    __syncthreads();                           // compiler drains vmcnt before barrier
    const int fr  = lane & 15;
    const int kof = (lane >> 4) * 8;
    bf16x8 af[4], bfr[4];
#pragma unroll
    for (int mi = 0; mi < 4; ++mi)
      af[mi] = *(const bf16x8*)&As[(wm + mi * 16 + fr) * 32 + kof];
#pragma unroll
    for (int ni = 0; ni < 4; ++ni)
      bfr[ni] = *(const bf16x8*)&Bs[(wn + ni * 16 + fr) * 32 + kof];
#pragma unroll
    for (int mi = 0; mi < 4; ++mi)
#pragma unroll
      for (int ni = 0; ni < 4; ++ni)
        acc[mi][ni] = __builtin_amdgcn_mfma_f32_16x16x32_bf16(af[mi], bfr[ni], acc[mi][ni], 0, 0, 0);
    __syncthreads();
  }

  // Epilogue.  C/D frag layout (m89-verified): col = lane&15, row = (lane>>4)*4 + r.
  const int col = lane & 15;
  const int rb  = (lane >> 4) * 4;
#pragma unroll
  for (int mi = 0; mi < 4; ++mi) {
#pragma unroll
    for (int ni = 0; ni < 4; ++ni) {
      const int mg = m0 + wm + mi * 16 + rb;
      const int ng = n0 + wn + ni * 16 + col;
      const float bvv = BIAS ? bias[ng] : 0.0f;
      if constexpr (CMODE == 2) {
        // transposed V write: 4 acc regs are 4 consecutive t -> one 8B store
        unsigned short* Cc = (unsigned short*)Cv;
        const long bb = mg >> 11;
        const int  t  = mg & 2047;
        union { unsigned short us[4]; unsigned long long ll; } u;
#pragma unroll
        for (int r = 0; r < 4; ++r) u.us[r] = f2bf(acc[mi][ni][r] * alpha + bvv);
        *(unsigned long long*)(Cc + bb * 4194304 + (long)ng * 2048 + t) = u.ll;
      } else if constexpr (CMODE == 1) {
        unsigned short* Cc = (unsigned short*)Cv + (long)bz * bsC;
#pragma unroll
        for (int r = 0; r < 4; ++r)
          Cc[(long)(mg + r) * ldc + ng] = f2bf(acc[mi][ni][r] * alpha + bvv);
      } else {
        float* Cf = (float*)Cv + (long)bz * bsC;
#pragma unroll
        for (int r = 0; r < 4; ++r)
          Cf[(long)(mg + r) * ldc + ng] = acc[mi][ni][r] * alpha + bvv;
      }
    }
  }
}

// ---------------- row softmax: fp32 scores row (2048) -> bf16 P in-place --------
// P row r (2048 bf16 = 4096B) is written into the first half of fp32 row r's own
// 8192B storage; each block reads its whole row before writing -> no hazard.
__global__ __launch_bounds__(256) void softmax_rows(float* __restrict__ Sc) {
  const int tid = threadIdx.x;
  const long row = blockIdx.x;
  float* srow = Sc + row * 2048;
  const float4 v0 = ((const float4*)srow)[tid * 2];
  const float4 v1 = ((const float4*)srow)[tid * 2 + 1];
  float mx = fmaxf(fmaxf(fmaxf(v0.x, v0.y), fmaxf(v0.z, v0.w)),
                   fmaxf(fmaxf(v1.x, v1.y), fmaxf(v1.z, v1.w)));
  __shared__ float red[8];
  const int lane = tid & 63, wid = tid >> 6;
#pragma unroll
  for (int off = 32; off; off >>= 1) mx = fmaxf(mx, __shfl_down(mx, off));
  if (!lane) red[wid] = mx;
  __syncthreads();
  mx = fmaxf(fmaxf(red[0], red[1]), fmaxf(red[2], red[3]));
  float e[8];
  e[0] = __expf(v0.x - mx); e[1] = __expf(v0.y - mx);
  e[2] = __expf(v0.z - mx); e[3] = __expf(v0.w - mx);
  e[4] = __expf(v1.x - mx); e[5] = __expf(v1.y - mx);
  e[6] = __expf(v1.z - mx); e[7] = __expf(v1.w - mx);
  float s = e[0] + e[1] + e[2] + e[3] + e[4] + e[5] + e[6] + e[7];
#pragma unroll
  for (int off = 32; off; off >>= 1) s += __shfl_down(s, off);
  if (!lane) red[4 + wid] = s;
  __syncthreads();
  s = red[4] + red[5] + red[6] + red[7];
  const float inv = 1.0f / s;
  union { unsigned short us[8]; int4 v; } u;
#pragma unroll
  for (int j = 0; j < 8; ++j) u.us[j] = f2bf(e[j] * inv);
  ((int4*)srow)[tid] = u.v;   // bytes [tid*16, tid*16+16) of this row's storage
}

extern "C" void kernel_launch(void* const* d_in, const int* in_sizes, int n_in,
                              void* d_out, int out_size, void* d_ws, size_t ws_size,
                              hipStream_t stream) {
  const float* X  = (const float*)d_in[0];
  const float* Wq = (const float*)d_in[1];
  const float* bq = (const float*)d_in[2];
  const float* Wk = (const float*)d_in[3];
  const float* bk = (const float*)d_in[4];
  const float* Wv = (const float*)d_in[5];
  const float* bv = (const float*)d_in[6];
  const float* Wo = (const float*)d_in[7];
  const float* bo = (const float*)d_in[8];
  float* out = (float*)d_out;

  // workspace carve-up (224 MiB total)
  char* w = (char*)d_ws;
  unsigned short* Xb  = (unsigned short*)w; w += (size_t)8192 * 1024 * 2;
  unsigned short* Wqb = (unsigned short*)w; w += (size_t)2048 * 1024 * 2;
  unsigned short* Wkb = (unsigned short*)w; w += (size_t)2048 * 1024 * 2;
  unsigned short* Wvb = (unsigned short*)w; w += (size_t)2048 * 1024 * 2;
  unsigned short* Wob = (unsigned short*)w; w += (size_t)1024 * 2048 * 2;
  unsigned short* Qb  = (unsigned short*)w; w += (size_t)8192 * 2048 * 2;
  unsigned short* Kb  = (unsigned short*)w; w += (size_t)8192 * 2048 * 2;
  unsigned short* Vt  = (unsigned short*)w; w += (size_t)8192 * 2048 * 2;  // [4][2048 d][2048 t]
  unsigned short* AO  = (unsigned short*)w; w += (size_t)8192 * 2048 * 2;
  float*          Sc  = (float*)w;          w += (size_t)4 * 2048 * 2048 * 4;
  if ((size_t)(w - (char*)d_ws) > ws_size) return;  // leaves zero output (absmax ~1.04)

  // converts
  cvt_f32_bf16<<<8192, 256, 0, stream>>>(X,  Xb,  8192 * 1024 / 4);
  cvt_f32_bf16<<<2048, 256, 0, stream>>>(Wq, Wqb, 2048 * 1024 / 4);
  cvt_f32_bf16<<<2048, 256, 0, stream>>>(Wk, Wkb, 2048 * 1024 / 4);
  cvt_f32_bf16<<<2048, 256, 0, stream>>>(Wv, Wvb, 2048 * 1024 / 4);
  cvt_f32_bf16<<<2048, 256, 0, stream>>>(Wo, Wob, 1024 * 2048 / 4);

  // projections: M=8192, N=2048, K=1024
  gemm_nt<1, true><<<dim3(16, 64, 1), 256, 0, stream>>>(Xb, Wqb, Qb, bq,
      1024, 1024, 1024, 2048, 0, 0, 0, 1.0f);
  gemm_nt<1, true><<<dim3(16, 64, 1), 256, 0, stream>>>(Xb, Wkb, Kb, bk,
      1024, 1024, 1024, 2048, 0, 0, 0, 1.0f);
  gemm_nt<2, true><<<dim3(16, 64, 1), 256, 0, stream>>>(Xb, Wvb, Vt, bv,
      1024, 1024, 1024, 0, 0, 0, 0, 1.0f);

  // scores: per-batch 2048x2048, K=2048, alpha = 1/sqrt(1024)
  gemm_nt<0, false><<<dim3(16, 16, 4), 256, 0, stream>>>(Qb, Kb, Sc, nullptr,
      2048, 2048, 2048, 2048, 4194304, 4194304, 4194304, 0.03125f);

  // softmax over all 8192 rows; writes bf16 P in-place (row stride 4096 bf16 elems)
  softmax_rows<<<8192, 256, 0, stream>>>(Sc);

  // O = P @ Vt^T : per-batch, A = bf16 view of Sc (lda 4096), B = Vt
  gemm_nt<1, false><<<dim3(16, 16, 4), 256, 0, stream>>>((unsigned short*)Sc, Vt, AO, nullptr,
      2048, 4096, 2048, 2048, 8388608, 4194304, 4194304, 1.0f);

  // out = AO @ Wo^T + bo : M=8192, N=1024, K=2048, fp32 out
  gemm_nt<0, true><<<dim3(8, 64, 1), 256, 0, stream>>>(AO, Wob, out, bo,
      2048, 2048, 2048, 1024, 0, 0, 0, 1.0f);
}

// Round 2
// 337.381 us; speedup vs baseline: 1.4725x; 1.4725x over previous
//
#include <hip/hip_runtime.h>

// ComplexAttention: B=4, S=2048, D=1024. Reduces to single-head attention with
// head_dim 2*D=2048:  Q/K/V = X@W^T+b ; S = Q@K^T/32 ; P = softmax(S) ; O = P@V ;
// out = O@Wo^T + bo.  All GEMMs: 256x256-tile 8-phase bf16 MFMA (m201 template).

typedef short  bf16x8 __attribute__((ext_vector_type(8)));
typedef float  f32x4  __attribute__((ext_vector_type(4)));
typedef unsigned short u16;

typedef __attribute__((address_space(3))) void       lds_void;
typedef const __attribute__((address_space(1))) void g_void;

__device__ __forceinline__ u16 f2bf(float f) {
  union { float f; unsigned u; } v; v.f = f;
  unsigned r = v.u + 0x7FFFu + ((v.u >> 16) & 1u);   // round-to-nearest-even
  return (u16)(r >> 16);
}

// ---------------- fp32 -> bf16 convert (vectorized) ----------------
__global__ __launch_bounds__(256) void cvt_f32_bf16(const float* __restrict__ in,
                                                    u16* __restrict__ out, int n4) {
  int i = blockIdx.x * 256 + threadIdx.x;
  if (i >= n4) return;
  const float4 v = ((const float4*)in)[i];
  union { u16 us[4]; unsigned long long ll; } u;
  u.us[0] = f2bf(v.x); u.us[1] = f2bf(v.y); u.us[2] = f2bf(v.z); u.us[3] = f2bf(v.w);
  ((unsigned long long*)out)[i] = u.ll;
}

// ---------------- 256x256 8-phase NT GEMM ----------------
// C[m,n] = alpha * sum_k A[m,k]*B[n,k] (+ bias[n]).  A,B bf16 row-major (K contig).
// CMODE: 0 = fp32 C, 1 = bf16 C, 2 = bf16 transposed-V write Vt[b][n][t] (b=m>>11, t=m&2047).
// 512 thr = 8 waves (2M x 4N); per-wave 128x64 out; BK=64; LDS 128 KiB dbuf.
// Swizzle: 16B chunk c of row r lives at slot c^(r&7) (G4 XOR; pre-swizzled gload src).
// Schedule (per iter = K-tiles t0=2j (buf0), t1=2j+1 (buf1)), counted vmcnt(6) at p4/p8:
//  p1: rd af0,bf0(buf0) | stage A1(t1)->b1      p5: rd af0,bf0(buf1) | stage A1(t0+2)->b0
//  p2: rd bf1(buf0)                             p6: rd bf1(buf1)
//  p3: rd af1(buf0)     | stage B0(t0+2)->b0    p7: rd af1(buf1)     | stage B0(t1+2)->b1
//  p4: stage B1,A0(t0+2)->b0 | vmcnt(6)         p8: stage B1,A0(t1+2)->b1 | vmcnt(6)
template<int CMODE, bool BIAS>
__global__ __launch_bounds__(512) void gemm256(const u16* __restrict__ A,
                                               const u16* __restrict__ B,
                                               void* __restrict__ Cv,
                                               const float* __restrict__ bias,
                                               int K, int lda, int ldb, int ldc,
                                               long bsA, long bsB, long bsC,
                                               float alpha)
{
  __shared__ u16 sm[65536];                  // A: [2][256][64] @ 0 ; B: same @ 32768
  const int bz = blockIdx.z;
  const u16* Ab = A + (long)bz * bsA;
  const u16* Bb = B + (long)bz * bsB;
  const int m0 = blockIdx.y * 256, n0 = blockIdx.x * 256;
  const int tid = threadIdx.x, lane = tid & 63, w = tid >> 6;
  const int wmr = w >> 2, wnr = w & 3;       // wave tile-row (0..1) / tile-col (0..3)
  const int fr = lane & 15, ko = lane >> 4;  // frag row, 16B-chunk within k

  f32x4 acc[8][4] = {};

  // stage one 128x64 half-tile (2 x global_load_lds of 16B per lane)
  auto STAGE = [&](int dbuf, int half, int t, bool isA) {
    const u16* src = isA ? Ab : Bb;
    const int ld = isA ? lda : ldb;
    const int r0 = (isA ? m0 : n0) + half * 128;
    u16* lb = sm + (isA ? 0 : 32768) + dbuf * 16384 + half * 8192;
#pragma unroll
    for (int q = 0; q < 2; ++q) {
      const int slot = q * 512 + w * 64 + lane;   // chunk id 0..1023
      const int rl = slot >> 3, cc = slot & 7;
      const int c = cc ^ (rl & 7);                // pre-swizzled source chunk
      __builtin_amdgcn_global_load_lds(
          (g_void*)(src + (long)(r0 + rl) * ld + t * 64 + c * 8),
          (lds_void*)(lb + q * 4096 + w * 512), 16, 0, 0);
    }
  };
  // A-frags: 4 m-frags x 2 k-slices for m-half mh -> dst[mi*2+kk]
  auto LDA_f = [&](bf16x8* dst, int dbuf, int mh) {
#pragma unroll
    for (int mi = 0; mi < 4; ++mi)
#pragma unroll
      for (int kk = 0; kk < 2; ++kk) {
        const int r = wmr * 128 + mh * 64 + mi * 16 + fr;
        const int c = kk * 4 + ko;
        dst[mi * 2 + kk] = *(const bf16x8*)(sm + dbuf * 16384 + r * 64 + ((c ^ (r & 7)) * 8));
      }
  };
  // B-frags: 2 n-frags x 2 k-slices for n-half nh -> dst[ni*2+kk]
  auto LDB_f = [&](bf16x8* dst, int dbuf, int nh) {
#pragma unroll
    for (int ni = 0; ni < 2; ++ni)
#pragma unroll
      for (int kk = 0; kk < 2; ++kk) {
        const int r = wnr * 64 + nh * 32 + ni * 16 + fr;
        const int c = kk * 4 + ko;
        dst[ni * 2 + kk] = *(const bf16x8*)(sm + 32768 + dbuf * 16384 + r * 64 + ((c ^ (r & 7)) * 8));
      }
  };
  // one phase's MFMA cluster: 4m x 2n x 2kk = 16 MFMA
  auto MM = [&](const bf16x8* af, const bf16x8* bf, int mb, int nb) {
    __builtin_amdgcn_s_setprio(1);
#pragma unroll
    for (int mi = 0; mi < 4; ++mi)
#pragma unroll
      for (int ni = 0; ni < 2; ++ni)
#pragma unroll
        for (int kk = 0; kk < 2; ++kk)
          acc[mb + mi][nb + ni] = __builtin_amdgcn_mfma_f32_16x16x32_bf16(
              af[mi * 2 + kk], bf[ni * 2 + kk], acc[mb + mi][nb + ni], 0, 0, 0);
    __builtin_amdgcn_s_setprio(0);
  };

  const int nt = K >> 6, niter = nt >> 1;

  // prologue: tile0 full -> buf0 ; B0,B1,A0 of tile1 -> buf1 (A1(1) staged at p1)
  STAGE(0, 0, 0, true);  STAGE(0, 1, 0, true);
  STAGE(0, 0, 0, false); STAGE(0, 1, 0, false);
  STAGE(1, 0, 1, false); STAGE(1, 1, 1, false);
  STAGE(1, 0, 1, true);
  asm volatile("s_waitcnt vmcnt(6)" ::: "memory");
  __builtin_amdgcn_s_barrier();

  bf16x8 af0[8], af1[8], bf0[4], bf1[4];
  for (int j = 0; j < niter; ++j) {
    const bool pre = (j < niter - 1);
    const int t0 = 2 * j, t1 = 2 * j + 1;
    // p1
    LDA_f(af0, 0, 0); LDB_f(bf0, 0, 0);
    STAGE(1, 1, t1, true);
    __builtin_amdgcn_s_barrier();
    MM(af0, bf0, 0, 0);
    __builtin_amdgcn_s_barrier();
    // p2
    LDB_f(bf1, 0, 1);
    __builtin_amdgcn_s_barrier();
    MM(af0, bf1, 0, 2);
    __builtin_amdgcn_s_barrier();
    // p3
    LDA_f(af1, 0, 1);
    if (pre) STAGE(0, 0, t0 + 2, false);
    __builtin_amdgcn_s_barrier();
    MM(af1, bf1, 4, 2);
    __builtin_amdgcn_s_barrier();
    // p4
    if (pre) { STAGE(0, 1, t0 + 2, false); STAGE(0, 0, t0 + 2, true); }
    __builtin_amdgcn_s_barrier();
    MM(af1, bf0, 4, 0);
    asm volatile("s_waitcnt vmcnt(6)" ::: "memory");
    __builtin_amdgcn_s_barrier();
    // p5
    LDA_f(af0, 1, 0); LDB_f(bf0, 1, 0);
    if (pre) STAGE(0, 1, t0 + 2, true);
    __builtin_amdgcn_s_barrier();
    MM(af0, bf0, 0, 0);
    __builtin_amdgcn_s_barrier();
    // p6
    LDB_f(bf1, 1, 1);
    __builtin_amdgcn_s_barrier();
    MM(af0, bf1, 0, 2);
    __builtin_amdgcn_s_barrier();
    // p7
    LDA_f(af1, 1, 1);
    if (pre) STAGE(1, 0, t1 + 2, false);
    __builtin_amdgcn_s_barrier();
    MM(af1, bf1, 4, 2);
    __builtin_amdgcn_s_barrier();
    // p8
    if (pre) { STAGE(1, 1, t1 + 2, false); STAGE(1, 0, t1 + 2, true); }
    __builtin_amdgcn_s_barrier();
    MM(af1, bf0, 4, 0);
    asm volatile("s_waitcnt vmcnt(6)" ::: "memory");
    __builtin_amdgcn_s_barrier();
  }

  // epilogue: C/D frag layout col=lane&15, row=(lane>>4)*4+r  (m89-verified)
  const int col = lane & 15, rb = (lane >> 4) * 4;
#pragma unroll
  for (int mi = 0; mi < 8; ++mi) {
#pragma unroll
    for (int ni = 0; ni < 4; ++ni) {
      const int mg = m0 + wmr * 128 + mi * 16 + rb;
      const int ng = n0 + wnr * 64 + ni * 16 + col;
      const float bvv = BIAS ? bias[ng] : 0.0f;
      if constexpr (CMODE == 2) {
        u16* Cc = (u16*)Cv;
        const long bb = mg >> 11;
        const int  t  = mg & 2047;
        union { u16 us[4]; unsigned long long ll; } u;
#pragma unroll
        for (int r = 0; r < 4; ++r) u.us[r] = f2bf(acc[mi][ni][r] * alpha + bvv);
        *(unsigned long long*)(Cc + bb * 4194304 + (long)ng * 2048 + t) = u.ll;
      } else if constexpr (CMODE == 1) {
        u16* Cc = (u16*)Cv + (long)bz * bsC;
#pragma unroll
        for (int r = 0; r < 4; ++r)
          Cc[(long)(mg + r) * ldc + ng] = f2bf(acc[mi][ni][r] * alpha + bvv);
      } else {
        float* Cf = (float*)Cv + (long)bz * bsC;
#pragma unroll
        for (int r = 0; r < 4; ++r)
          Cf[(long)(mg + r) * ldc + ng] = acc[mi][ni][r] * alpha + bvv;
      }
    }
  }
}

// ---------------- row softmax: fp32 scores row (2048) -> bf16 P in-place --------
__global__ __launch_bounds__(256) void softmax_rows(float* __restrict__ Sc) {
  const int tid = threadIdx.x;
  const long row = blockIdx.x;
  float* srow = Sc + row * 2048;
  const float4 v0 = ((const float4*)srow)[tid * 2];
  const float4 v1 = ((const float4*)srow)[tid * 2 + 1];
  float mx = fmaxf(fmaxf(fmaxf(v0.x, v0.y), fmaxf(v0.z, v0.w)),
                   fmaxf(fmaxf(v1.x, v1.y), fmaxf(v1.z, v1.w)));
  __shared__ float red[8];
  const int lane = tid & 63, wid = tid >> 6;
#pragma unroll
  for (int off = 32; off; off >>= 1) mx = fmaxf(mx, __shfl_down(mx, off));
  if (!lane) red[wid] = mx;
  __syncthreads();
  mx = fmaxf(fmaxf(red[0], red[1]), fmaxf(red[2], red[3]));
  float e[8];
  e[0] = __expf(v0.x - mx); e[1] = __expf(v0.y - mx);
  e[2] = __expf(v0.z - mx); e[3] = __expf(v0.w - mx);
  e[4] = __expf(v1.x - mx); e[5] = __expf(v1.y - mx);
  e[6] = __expf(v1.z - mx); e[7] = __expf(v1.w - mx);
  float s = e[0] + e[1] + e[2] + e[3] + e[4] + e[5] + e[6] + e[7];
#pragma unroll
  for (int off = 32; off; off >>= 1) s += __shfl_down(s, off);
  if (!lane) red[4 + wid] = s;
  __syncthreads();
  s = red[4] + red[5] + red[6] + red[7];
  const float inv = 1.0f / s;
  union { u16 us[8]; int4 v; } u;
#pragma unroll
  for (int j = 0; j < 8; ++j) u.us[j] = f2bf(e[j] * inv);
  ((int4*)srow)[tid] = u.v;
}

extern "C" void kernel_launch(void* const* d_in, const int* in_sizes, int n_in,
                              void* d_out, int out_size, void* d_ws, size_t ws_size,
                              hipStream_t stream) {
  const float* X  = (const float*)d_in[0];
  const float* Wq = (const float*)d_in[1];
  const float* bq = (const float*)d_in[2];
  const float* Wk = (const float*)d_in[3];
  const float* bk = (const float*)d_in[4];
  const float* Wv = (const float*)d_in[5];
  const float* bv = (const float*)d_in[6];
  const float* Wo = (const float*)d_in[7];
  const float* bo = (const float*)d_in[8];
  float* out = (float*)d_out;

  char* w = (char*)d_ws;
  u16* Xb  = (u16*)w; w += (size_t)8192 * 1024 * 2;
  u16* Wqb = (u16*)w; w += (size_t)2048 * 1024 * 2;
  u16* Wkb = (u16*)w; w += (size_t)2048 * 1024 * 2;
  u16* Wvb = (u16*)w; w += (size_t)2048 * 1024 * 2;
  u16* Wob = (u16*)w; w += (size_t)1024 * 2048 * 2;
  u16* Qb  = (u16*)w; w += (size_t)8192 * 2048 * 2;
  u16* Kb  = (u16*)w; w += (size_t)8192 * 2048 * 2;
  u16* Vt  = (u16*)w; w += (size_t)8192 * 2048 * 2;   // [4][2048 d][2048 t]
  u16* AO  = (u16*)w; w += (size_t)8192 * 2048 * 2;
  float* Sc = (float*)w; w += (size_t)4 * 2048 * 2048 * 4;
  if ((size_t)(w - (char*)d_ws) > ws_size) return;

  cvt_f32_bf16<<<8192, 256, 0, stream>>>(X,  Xb,  8192 * 1024 / 4);
  cvt_f32_bf16<<<2048, 256, 0, stream>>>(Wq, Wqb, 2048 * 1024 / 4);
  cvt_f32_bf16<<<2048, 256, 0, stream>>>(Wk, Wkb, 2048 * 1024 / 4);
  cvt_f32_bf16<<<2048, 256, 0, stream>>>(Wv, Wvb, 2048 * 1024 / 4);
  cvt_f32_bf16<<<2048, 256, 0, stream>>>(Wo, Wob, 1024 * 2048 / 4);

  // projections: M=8192, N=2048, K=1024
  gemm256<1, true><<<dim3(8, 32, 1), 512, 0, stream>>>(Xb, Wqb, Qb, bq,
      1024, 1024, 1024, 2048, 0, 0, 0, 1.0f);
  gemm256<1, true><<<dim3(8, 32, 1), 512, 0, stream>>>(Xb, Wkb, Kb, bk,
      1024, 1024, 1024, 2048, 0, 0, 0, 1.0f);
  gemm256<2, true><<<dim3(8, 32, 1), 512, 0, stream>>>(Xb, Wvb, Vt, bv,
      1024, 1024, 1024, 0, 0, 0, 0, 1.0f);

  // scores: per-batch 2048x2048, K=2048, alpha = 1/sqrt(1024)
  gemm256<0, false><<<dim3(8, 8, 4), 512, 0, stream>>>(Qb, Kb, Sc, nullptr,
      2048, 2048, 2048, 2048, 4194304, 4194304, 4194304, 0.03125f);

  softmax_rows<<<8192, 256, 0, stream>>>(Sc);

  // O = P @ Vt^T : A = bf16 P view of Sc (lda 4096)
  gemm256<1, false><<<dim3(8, 8, 4), 512, 0, stream>>>((u16*)Sc, Vt, AO, nullptr,
      2048, 4096, 2048, 2048, 8388608, 4194304, 4194304, 1.0f);

  // out = AO @ Wo^T + bo : M=8192, N=1024, K=2048, fp32 out
  gemm256<0, true><<<dim3(4, 32, 1), 512, 0, stream>>>(AO, Wob, out, bo,
      2048, 2048, 2048, 1024, 0, 0, 0, 1.0f);
}